// Round 1
// 61.826 us; speedup vs baseline: 1.0326x; 1.0326x over previous
//
#include <hip/hip_runtime.h>
#include <math.h>

#define BATCH   512
#define NPATCH  196   // 14*14

// ---------------------------------------------------------------------------
// State idx = w0*8 + w1*4 + w2*2 + w3 (wire 0 = MSB). MASK = 8 >> wire.
// All loops fully unrolled with compile-time indices -> arrays live in VGPRs.
// ---------------------------------------------------------------------------

// RY on a purely REAL state (valid until the first RZ): half the work.
template <int MASK>
__device__ __forceinline__ void ry_real(float* s, float c, float sn) {
    #pragma unroll
    for (int i = 0; i < 16; ++i) {
        if (!(i & MASK)) {
            const int j = i | MASK;
            float a0 = s[i], a1 = s[j];
            s[i] = c * a0 - sn * a1;
            s[j] = sn * a0 + c * a1;
        }
    }
}

template <int MASK>
__device__ __forceinline__ void ry_cplx(float* sr, float* si, float c, float sn) {
    #pragma unroll
    for (int i = 0; i < 16; ++i) {
        if (!(i & MASK)) {
            const int j = i | MASK;
            float a0 = sr[i], a1 = sr[j];
            sr[i] = c * a0 - sn * a1;
            sr[j] = sn * a0 + c * a1;
            float b0 = si[i], b1 = si[j];
            si[i] = c * b0 - sn * b1;
            si[j] = sn * b0 + c * b1;
        }
    }
}

template <int CMASK, int TMASK>
__device__ __forceinline__ void cnot_real(float* s) {
    #pragma unroll
    for (int i = 0; i < 16; ++i) {
        if ((i & CMASK) && !(i & TMASK)) {
            const int j = i | TMASK;
            float t = s[i]; s[i] = s[j]; s[j] = t;
        }
    }
}

template <int CMASK, int TMASK>
__device__ __forceinline__ void cnot_cplx(float* sr, float* si) {
    #pragma unroll
    for (int i = 0; i < 16; ++i) {
        if ((i & CMASK) && !(i & TMASK)) {
            const int j = i | TMASK;
            float t;
            t = sr[i]; sr[i] = sr[j]; sr[j] = t;
            t = si[i]; si[i] = si[j]; si[j] = t;
        }
    }
}

// ---------------------------------------------------------------------------
// One block per patch location (196 blocks x 512 threads).
// Thread t owns batch t: computes stats contribution + ONE circuit.
//
// Gate tables in LDS (thread-uniform broadcasts):
//   s_ryc/s_rys[16] : cos/sin(theta/2) of the 16 RY gates, idx = l*8 + set*4 + w
//   s_pc/s_ps[16]   : combined layer-0 RZ phase per basis state
//                     alpha_i = sum_w (bit_w(i) ? +th_w/2 : -th_w/2)
// Layer-1 (l=1) RZs are dropped entirely: diagonal before measurement.
// ---------------------------------------------------------------------------
__global__ __launch_bounds__(512) void fused_kernel(const float* __restrict__ x,
                                                    const float* __restrict__ params,
                                                    float* __restrict__ out) {
    __shared__ float s_ryc[16], s_rys[16];
    __shared__ float s_pc[16], s_ps[16];
    __shared__ float s_sum[8], s_sq[8];
    __shared__ float s_m, s_invh;

    const int p = blockIdx.x;             // 0..195
    const int r = p / 14, c = p - r * 14;
    const int t = threadIdx.x;            // 0..511

    // ---- thread-uniform gate tables, once per block ----
    if (t < 16) {
        const int l = t >> 3, set = (t >> 2) & 1, w = t & 3;
        float sn, cs;
        __sincosf(0.5f * params[l * 12 + w * 3 + set], &sn, &cs);
        s_ryc[t] = cs;
        s_rys[t] = sn;
    } else if (t < 32) {
        const int i = t - 16;
        const float h0 = 0.5f * params[0 * 3 + 2];
        const float h1 = 0.5f * params[1 * 3 + 2];
        const float h2 = 0.5f * params[2 * 3 + 2];
        const float h3 = 0.5f * params[3 * 3 + 2];
        const float alpha = ((i & 8) ? h0 : -h0) + ((i & 4) ? h1 : -h1)
                          + ((i & 2) ? h2 : -h2) + ((i & 1) ? h3 : -h3);
        float sn, cs;
        __sincosf(alpha, &sn, &cs);
        s_pc[i] = cs;
        s_ps[i] = sn;
    }

    // ---- per-thread patch load (batch t) ----
    const float* base = x + t * 784 + (2 * r) * 28 + 2 * c;
    const float2 a01 = *(const float2*)base;
    const float2 a23 = *(const float2*)(base + 28);

    // ---- per-location normalization stats over 512*4 values ----
    float sum = a01.x + a01.y + a23.x + a23.y;
    float sq  = a01.x * a01.x + a01.y * a01.y + a23.x * a23.x + a23.y * a23.y;
    #pragma unroll
    for (int off = 32; off; off >>= 1) {
        sum += __shfl_down(sum, off, 64);
        sq  += __shfl_down(sq,  off, 64);
    }
    const int wave = t >> 6, lane = t & 63;
    if (lane == 0) { s_sum[wave] = sum; s_sq[wave] = sq; }
    __syncthreads();
    if (t == 0) {
        float S = 0.f, Q = 0.f;
        #pragma unroll
        for (int w = 0; w < 8; ++w) { S += s_sum[w]; Q += s_sq[w]; }
        const float n = (float)(BATCH * 4);
        float m   = S / n;
        float var = (Q - S * S / n) / (n - 1.0f);
        float sd  = sqrtf(fmaxf(var, 0.f));
        s_m    = m;
        // angle = (v - m)/(sd + 1e-8) * pi; gates use theta/2 -> fold the 0.5
        s_invh = 0.5f * 3.14159265358979323846f / (sd + 1e-8f);
    }
    __syncthreads();

    const float m    = s_m;
    const float invh = s_invh;

    // ---- input RY half-angles ----
    float c0, s0, c1, s1, c2, s2, c3, s3;
    __sincosf((a01.x - m) * invh, &s0, &c0);
    __sincosf((a01.y - m) * invh, &s1, &c1);
    __sincosf((a23.x - m) * invh, &s2, &c2);
    __sincosf((a23.y - m) * invh, &s3, &c3);

    // ---- initial product state (REAL) ----
    float sr[16];
    {
        const float cc01 = c0 * c1, cs01 = c0 * s1, sc01 = s0 * c1, ss01 = s0 * s1;
        const float cc23 = c2 * c3, cs23 = c2 * s3, sc23 = s2 * c3, ss23 = s2 * s3;
        #pragma unroll
        for (int i = 0; i < 16; ++i) {
            const float hi = (i & 8) ? ((i & 4) ? ss01 : sc01) : ((i & 4) ? cs01 : cc01);
            const float lo = (i & 2) ? ((i & 1) ? ss23 : sc23) : ((i & 1) ? cs23 : cc23);
            sr[i] = hi * lo;
        }
    }

    // ---- layer 0: all-real RYs + CNOTs ----
    ry_real<8>(sr, s_ryc[0], s_rys[0]);
    ry_real<4>(sr, s_ryc[1], s_rys[1]);
    ry_real<2>(sr, s_ryc[2], s_rys[2]);
    ry_real<1>(sr, s_ryc[3], s_rys[3]);
    cnot_real<8, 4>(sr);
    cnot_real<4, 2>(sr);
    cnot_real<2, 1>(sr);
    ry_real<8>(sr, s_ryc[4], s_rys[4]);
    ry_real<4>(sr, s_ryc[5], s_rys[5]);
    ry_real<2>(sr, s_ryc[6], s_rys[6]);
    ry_real<1>(sr, s_ryc[7], s_rys[7]);
    cnot_real<4, 8>(sr);
    cnot_real<2, 4>(sr);
    cnot_real<1, 2>(sr);

    // ---- layer-0 RZs: one combined diagonal phase on the real state ----
    float si[16];
    #pragma unroll
    for (int i = 0; i < 16; ++i) {
        si[i] = sr[i] * s_ps[i];
        sr[i] = sr[i] * s_pc[i];
    }

    // ---- layer 1: complex RYs + CNOTs; trailing RZs dropped (diagonal) ----
    ry_cplx<8>(sr, si, s_ryc[8],  s_rys[8]);
    ry_cplx<4>(sr, si, s_ryc[9],  s_rys[9]);
    ry_cplx<2>(sr, si, s_ryc[10], s_rys[10]);
    ry_cplx<1>(sr, si, s_ryc[11], s_rys[11]);
    cnot_cplx<8, 4>(sr, si);
    cnot_cplx<4, 2>(sr, si);
    cnot_cplx<2, 1>(sr, si);
    ry_cplx<8>(sr, si, s_ryc[12], s_rys[12]);
    ry_cplx<4>(sr, si, s_ryc[13], s_rys[13]);
    ry_cplx<2>(sr, si, s_ryc[14], s_rys[14]);
    ry_cplx<1>(sr, si, s_ryc[15], s_rys[15]);
    cnot_cplx<4, 8>(sr, si);
    cnot_cplx<2, 4>(sr, si);
    cnot_cplx<1, 2>(sr, si);

    // ---- probabilities + Walsh-tree Z expectations ----
    float pr[16];
    #pragma unroll
    for (int i = 0; i < 16; ++i) pr[i] = sr[i] * sr[i] + si[i] * si[i];

    float a[8], z3 = 0.f;
    #pragma unroll
    for (int k = 0; k < 8; ++k) {
        a[k] = pr[2 * k] + pr[2 * k + 1];
        z3  += pr[2 * k] - pr[2 * k + 1];
    }
    float b[4], z2 = 0.f;
    #pragma unroll
    for (int k = 0; k < 4; ++k) {
        b[k] = a[2 * k] + a[2 * k + 1];
        z2  += a[2 * k] - a[2 * k + 1];
    }
    float g2[2], z1 = 0.f;
    #pragma unroll
    for (int k = 0; k < 2; ++k) {
        g2[k] = b[2 * k] + b[2 * k + 1];
        z1   += b[2 * k] - b[2 * k + 1];
    }
    const float z0 = g2[0] - g2[1];

    *(float4*)(out + t * (NPATCH * 4) + p * 4) = make_float4(z0, z1, z2, z3);
}

extern "C" void kernel_launch(void* const* d_in, const int* in_sizes, int n_in,
                              void* d_out, int out_size, void* d_ws, size_t ws_size,
                              hipStream_t stream) {
    (void)in_sizes; (void)n_in; (void)d_ws; (void)ws_size; (void)out_size;
    const float* x      = (const float*)d_in[0];   // (512, 28, 28) fp32
    const float* params = (const float*)d_in[1];   // (2, 4, 3) fp32
    float*       out    = (float*)d_out;           // (512, 784) fp32

    fused_kernel<<<NPATCH, 512, 0, stream>>>(x, params, out);
}